// Round 1
// baseline (3519.403 us; speedup 1.0000x reference)
//
#include <hip/hip_runtime.h>

namespace {

constexpr int B = 4, L = 2048, H = 8, E = 64;
constexpr int ROWS = 32;              // q-rows per wave (lane pairs)
constexpr float SCALE = 0.125f;       // 1/sqrt(64)

__global__ __launch_bounds__(64)
void fa_fwd(const float* __restrict__ Q, const float* __restrict__ K,
            const float* __restrict__ V, float* __restrict__ O)
{
  const int lane = threadIdx.x & 63;
  const int pair = lane >> 1;         // row within tile: 0..31
  const int half = lane & 1;          // dim half: 0 -> 0..31, 1 -> 32..63
  const int tile = (int)gridDim.x - 1 - (int)blockIdx.x;  // longest tiles first
  const int bh   = (int)blockIdx.y;
  const int b = bh >> 3;              // H == 8
  const int h = bh & 7;
  const int r = tile * ROWS + pair;   // this thread's query row

  const size_t rowStride = (size_t)H * E;  // 512 floats
  const size_t baseBH = (size_t)b * L * rowStride + (size_t)h * E + (size_t)half * 32;

  // load q row (this thread's 32 dims)
  const float4* q4 = reinterpret_cast<const float4*>(Q + baseBH + (size_t)r * rowStride);
  float4 qv[8];
#pragma unroll
  for (int i = 0; i < 8; ++i) qv[i] = q4[i];

  float acc[32];
#pragma unroll
  for (int i = 0; i < 32; ++i) acc[i] = 0.0f;
  float m = -1e30f, lsum = 0.0f;

  const float* kb = K + baseBH;
  const float* vb = V + baseBH;
  const int smax = tile * ROWS + (ROWS - 1);  // uniform loop bound across wave

  for (int s = 0; s <= smax; ++s) {
    const float4* k4 = reinterpret_cast<const float4*>(kb + (size_t)s * rowStride);
    // 4 independent FMA chains to shorten dependency path
    float p0 = 0.f, p1 = 0.f, p2 = 0.f, p3 = 0.f;
#pragma unroll
    for (int i = 0; i < 8; ++i) {
      float4 kv = k4[i];
      p0 += qv[i].x * kv.x;
      p1 += qv[i].y * kv.y;
      p2 += qv[i].z * kv.z;
      p3 += qv[i].w * kv.w;
    }
    const float part = (p0 + p1) + (p2 + p3);
    const float dot = part + __shfl_xor(part, 1, 64);
    const float x = SCALE * dot;
    if (s <= r) {                     // causal: diagonal visible
      if (x > m) {                    // rare rescale (running max grew)
        const float corr = __expf(m - x);   // expf(-1e30-x) == 0 on first hit
        lsum *= corr;
#pragma unroll
        for (int i = 0; i < 32; ++i) acc[i] *= corr;
        m = x;
      }
      const float p = __expf(x - m);
      lsum += p;
      const float4* v4 = reinterpret_cast<const float4*>(vb + (size_t)s * rowStride);
#pragma unroll
      for (int i = 0; i < 8; ++i) {
        float4 vv = v4[i];
        acc[4*i+0] += p * vv.x;
        acc[4*i+1] += p * vv.y;
        acc[4*i+2] += p * vv.z;
        acc[4*i+3] += p * vv.w;
      }
    }
  }

  const float inv = 1.0f / lsum;
  float4* o4 = reinterpret_cast<float4*>(O + baseBH + (size_t)r * rowStride);
#pragma unroll
  for (int i = 0; i < 8; ++i) {
    o4[i] = make_float4(acc[4*i+0]*inv, acc[4*i+1]*inv,
                        acc[4*i+2]*inv, acc[4*i+3]*inv);
  }
}

} // namespace

extern "C" void kernel_launch(void* const* d_in, const int* in_sizes, int n_in,
                              void* d_out, int out_size, void* d_ws, size_t ws_size,
                              hipStream_t stream) {
  const float* Q = (const float*)d_in[0];
  const float* K = (const float*)d_in[1];
  const float* V = (const float*)d_in[2];
  float* O = (float*)d_out;
  (void)in_sizes; (void)n_in; (void)out_size; (void)d_ws; (void)ws_size;

  dim3 grid(L / ROWS, B * H);   // 64 tiles x 32 (b,h)
  fa_fwd<<<grid, 64, 0, stream>>>(Q, K, V, O);
}

// Round 2
// 185.129 us; speedup vs baseline: 19.0106x; 19.0106x over previous
//
#include <hip/hip_runtime.h>

namespace {

constexpr int B = 4, L = 2048, H = 8, E = 64;
constexpr int RS = H * E;           // 512 floats: row stride in [B,L,H,E]
constexpr float SCALE = 0.125f;     // 1/sqrt(64)

typedef __attribute__((ext_vector_type(8))) short bf16x8;
typedef __attribute__((ext_vector_type(4))) float f32x4;

__device__ inline short f2bf(float f) {
  union { float f; unsigned u; } c; c.f = f;
  unsigned r = (c.u + 0x7FFFu + ((c.u >> 16) & 1u)) >> 16;   // RNE
  return (short)r;
}

__device__ inline bf16x8 pack8(float4 a, float4 b) {
  bf16x8 r;
  r[0] = f2bf(a.x); r[1] = f2bf(a.y); r[2] = f2bf(a.z); r[3] = f2bf(a.w);
  r[4] = f2bf(b.x); r[5] = f2bf(b.y); r[6] = f2bf(b.z); r[7] = f2bf(b.w);
  return r;
}

// One wave handles 16 q-rows for one (b,h). Swapped S^T = K·Q^T so the
// softmax row lives lane-locally and P feeds PV's A-operand in place.
__global__ __launch_bounds__(256)
void fa_mfma(const float* __restrict__ Q, const float* __restrict__ K,
             const float* __restrict__ V, float* __restrict__ O)
{
  const int lane = threadIdx.x & 63;
  const int wv   = threadIdx.x >> 6;
  const int task = (int)blockIdx.x * 4 + wv;        // 0..4095
  const int bh   = task & 31;
  const int q16  = 127 - (task >> 5);               // longest tasks first
  const int b = bh >> 3, h = bh & 7;

  const int ln = lane & 15;                          // row/col within 16-tile
  const int lg = lane >> 4;                          // lane group 0..3
  const int d0 = lg * 4;

  const size_t base = (size_t)b * L * RS + (size_t)h * E;
  const float* Qb = Q + base;
  const float* Kb = K + base;
  const float* Vb = V + base;
  float*       Ob = O + base;

  const int qrow0 = q16 * 16;

  // Q fragments (B-operand: col = q-row qrow0+ln; k-dims d0.. pattern)
  const float* qp = Qb + (size_t)(qrow0 + ln) * RS;
  const bf16x8 qf0 = pack8(*(const float4*)(qp + d0),      *(const float4*)(qp + d0 + 16));
  const bf16x8 qf1 = pack8(*(const float4*)(qp + d0 + 32), *(const float4*)(qp + d0 + 48));

  f32x4 acc[4];                     // [nt]: dim = ln+16*nt, q-row = d0+r
#pragma unroll
  for (int nt = 0; nt < 4; ++nt) acc[nt] = (f32x4){0.f, 0.f, 0.f, 0.f};
  float m = -1e30f, lsum = 0.f;

  const int qmax   = qrow0 + 15;
  const int nsteps = (qmax >> 5) + 1;

  for (int step = 0; step < nsteps; ++step) {
    const int kv0 = step * 32;

    // ---- K fragments (A-operand: row = key; two 16-key blocks) ----
    const float* kp0 = Kb + (size_t)(kv0 + ln) * RS;
    const float* kp1 = kp0 + (size_t)16 * RS;
    const bf16x8 kf00 = pack8(*(const float4*)(kp0 + d0),      *(const float4*)(kp0 + d0 + 16));
    const bf16x8 kf01 = pack8(*(const float4*)(kp0 + d0 + 32), *(const float4*)(kp0 + d0 + 48));
    const bf16x8 kf10 = pack8(*(const float4*)(kp1 + d0),      *(const float4*)(kp1 + d0 + 16));
    const bf16x8 kf11 = pack8(*(const float4*)(kp1 + d0 + 32), *(const float4*)(kp1 + d0 + 48));

    f32x4 st0 = (f32x4){0.f,0.f,0.f,0.f}, st1 = st0;
    st0 = __builtin_amdgcn_mfma_f32_16x16x32_bf16(kf00, qf0, st0, 0, 0, 0);
    st0 = __builtin_amdgcn_mfma_f32_16x16x32_bf16(kf01, qf1, st0, 0, 0, 0);
    st1 = __builtin_amdgcn_mfma_f32_16x16x32_bf16(kf10, qf0, st1, 0, 0, 0);
    st1 = __builtin_amdgcn_mfma_f32_16x16x32_bf16(kf11, qf1, st1, 0, 0, 0);

    // ---- per-lane scores: 8 keys of its q-row (qrow0+ln) ----
    float x[8];
#pragma unroll
    for (int r = 0; r < 4; ++r) { x[r] = SCALE * st0[r]; x[4 + r] = SCALE * st1[r]; }

    if (step == nsteps - 1) {       // only the last step crosses the diagonal
      const int qr = qrow0 + ln;
#pragma unroll
      for (int e = 0; e < 8; ++e) {
        const int key = kv0 + ((e >> 2) << 4) + d0 + (e & 3);
        if (key > qr) x[e] = -1e30f;
      }
    }

    // ---- online softmax (state replicated across the 4-lane group) ----
    float mx = x[0];
#pragma unroll
    for (int e = 1; e < 8; ++e) mx = fmaxf(mx, x[e]);
    mx = fmaxf(mx, __shfl_xor(mx, 16, 64));
    mx = fmaxf(mx, __shfl_xor(mx, 32, 64));
    const float newm = fmaxf(m, mx);
    const float sc = __expf(m - newm);
    float p[8]; float ps = 0.f;
#pragma unroll
    for (int e = 0; e < 8; ++e) { p[e] = __expf(x[e] - newm); ps += p[e]; }
    ps += __shfl_xor(ps, 16, 64);
    ps += __shfl_xor(ps, 32, 64);
    lsum = lsum * sc + ps;
    m = newm;

    // rescale factors for the rows this lane accumulates (rows d0+r)
    float scr[4];
#pragma unroll
    for (int r = 0; r < 4; ++r) scr[r] = __shfl(sc, d0 + r, 64);
#pragma unroll
    for (int nt = 0; nt < 4; ++nt) {
      acc[nt][0] *= scr[0]; acc[nt][1] *= scr[1];
      acc[nt][2] *= scr[2]; acc[nt][3] *= scr[3];
    }

    // ---- P fragment (in place: e = key slot, matches A-layout) ----
    bf16x8 pf;
#pragma unroll
    for (int e = 0; e < 8; ++e) pf[e] = f2bf(p[e]);

    // ---- V fragments (B-operand: col = dim ln+16nt, k = key) + PV ----
    const float* vp0 = Vb + (size_t)kv0 * RS + ln;
#pragma unroll
    for (int nt = 0; nt < 4; ++nt) {
      const float* vp = vp0 + 16 * nt;
      bf16x8 vf;
#pragma unroll
      for (int e = 0; e < 8; ++e) {
        const int key = ((e >> 2) << 4) + d0 + (e & 3);
        vf[e] = f2bf(vp[(size_t)key * RS]);
      }
      acc[nt] = __builtin_amdgcn_mfma_f32_16x16x32_bf16(pf, vf, acc[nt], 0, 0, 0);
    }
  }

  // ---- epilogue: normalize and store ----
  const float il = 1.0f / lsum;     // inverse sum for row ln
  float inv[4];
#pragma unroll
  for (int r = 0; r < 4; ++r) inv[r] = __shfl(il, d0 + r, 64);

#pragma unroll
  for (int nt = 0; nt < 4; ++nt) {
#pragma unroll
    for (int r = 0; r < 4; ++r) {
      Ob[(size_t)(qrow0 + d0 + r) * RS + (ln + 16 * nt)] = acc[nt][r] * inv[r];
    }
  }
}

} // namespace

extern "C" void kernel_launch(void* const* d_in, const int* in_sizes, int n_in,
                              void* d_out, int out_size, void* d_ws, size_t ws_size,
                              hipStream_t stream) {
  const float* Q = (const float*)d_in[0];
  const float* K = (const float*)d_in[1];
  const float* V = (const float*)d_in[2];
  float* O = (float*)d_out;
  (void)in_sizes; (void)n_in; (void)out_size; (void)d_ws; (void)ws_size;

  const int tasks = (L / 16) * B * H;     // 4096 wave-tasks
  fa_mfma<<<tasks / 4, 256, 0, stream>>>(Q, K, V, O);
}